// Round 9
// baseline (904.198 us; speedup 1.0000x reference)
//
#include <hip/hip_runtime.h>

#define N_NODES 100000
#define N_PAD   100096
#define N_EDGES 1600000
#define NGRAPH  64
#define NHEAD   8
#define NCH     16
#define HID     128
#define IN0     288
#define NREL    51
#define EMB     256
#define NBBOX   32
#define NTOK    151
#define NEG_SLOPE 0.2f
#define EPS_BN  1e-5f
#define AGG_BLOCKS 2048
#define POOL_BLOCKS 1024
#define SENT 0x03F00000u          /* rel=63, src=0 */
#define SENT_MIN ((uint)(NREL) << 20)
#define L2E 1.4426950408889634f

typedef unsigned int uint;
typedef unsigned short ushort;

typedef __bf16 bf16_t;
typedef bf16_t bfx8 __attribute__((ext_vector_type(8)));
typedef float  fx4  __attribute__((ext_vector_type(4)));
typedef float  v2f  __attribute__((ext_vector_type(2)));

__device__ __forceinline__ ushort f2bf(float f) {
  uint u = __float_as_uint(f);
  u += 0x7fffu + ((u >> 16) & 1u);
  return (ushort)(u >> 16);
}
__device__ __forceinline__ float bf2f(uint u) { return __uint_as_float(u << 16); }
__device__ __forceinline__ v2f up2(uint u) {
  v2f r;
  r.x = __uint_as_float(u << 16);
  r.y = __uint_as_float(u & 0xffff0000u);
  return r;
}
__device__ __forceinline__ void unpack8(uint4 u, float* f) {
  f[0] = __uint_as_float(u.x << 16); f[1] = __uint_as_float(u.x & 0xffff0000u);
  f[2] = __uint_as_float(u.y << 16); f[3] = __uint_as_float(u.y & 0xffff0000u);
  f[4] = __uint_as_float(u.z << 16); f[5] = __uint_as_float(u.z & 0xffff0000u);
  f[6] = __uint_as_float(u.w << 16); f[7] = __uint_as_float(u.w & 0xffff0000u);
}

// W0cat(c, j): j<128 -> Wl0[c][j], j>=128 -> Wr0[c][j-128]
__device__ __forceinline__ float w0cat(const float* Wl0, const float* Wr0, int c, int j) {
  return (j < 128) ? Wl0[c * 128 + j] : Wr0[c * 128 + (j - 128)];
}

// ---------------- prep: WST transpose->bf16, ee tables, biascat, layer-0 folded tables T/F/c ----------------
#define S0 (2 * 256 * HID)
#define S1 (3 * NREL * HID)
#define S2 (3 * 256)
#define S3 (NTOK * 256)
#define S4 (4 * 256)
#define S5 (256)
#define PREP_TOT (S0 + S1 + S2 + S3 + S4 + S5)
__global__ void se_prep(const float* __restrict__ Wl0, const float* __restrict__ Wr0,
                        const float* __restrict__ WlS, const float* __restrict__ WrS,
                        const float* __restrict__ rel_emb, const float* __restrict__ We0,
                        const float* __restrict__ WeS,
                        const float* __restrict__ bl0, const float* __restrict__ br0,
                        const float* __restrict__ blS, const float* __restrict__ brS,
                        const float* __restrict__ tok_emb, const float* __restrict__ bbox_W,
                        const float* __restrict__ bbox_b,
                        ushort* __restrict__ WST, float* __restrict__ eetab,
                        float* __restrict__ biascat,
                        float* __restrict__ T, float* __restrict__ F, float* __restrict__ cvec) {
  int i = blockIdx.x * 256 + threadIdx.x;
  if (i < S0) {                              // WST[l][j][k] = (Wl|Wr)S[l][k][j] as bf16
    int li = i >> 15;
    int rem = i & 32767;
    int j = rem >> 7, k = rem & 127;
    float v = (j < 128) ? WlS[(li * 128 + k) * 128 + j] : WrS[(li * 128 + k) * 128 + (j - 128)];
    WST[(li * 256 + j) * 128 + k] = f2bf(v);
    return;
  }
  i -= S0;
  if (i < S1) {                              // eetab[l][r][j] = sum_c rel[r][c]*We_l[c][j]
    int li = i / (NREL * HID);
    int rem = i - li * (NREL * HID);
    int r = rem >> 7, j = rem & 127;
    const float* We = (li == 0) ? We0 : (WeS + (li - 1) * NCH * HID);
    float s = 0.f;
#pragma unroll
    for (int c = 0; c < NCH; c++) s += rel_emb[r * NCH + c] * We[c * HID + j];
    eetab[li * (NREL * HID) + rem] = s;
    return;
  }
  i -= S1;
  if (i < S2) {                              // biascat[l][256] = bl|br
    int li = i >> 8, j = i & 255;
    const float* bl = (li == 0) ? bl0 : (blS + (li - 1) * HID);
    const float* br = (li == 0) ? br0 : (brS + (li - 1) * HID);
    biascat[i] = (j < 128) ? bl[j] : br[j - 128];
    return;
  }
  i -= S2;
  if (i < S3) {                              // T[t][j] = sum_c tok_emb[t][c] * W0cat(c, j)
    int t = i >> 8, j = i & 255;
    float s = 0.f;
    for (int c = 0; c < EMB; c++) s += tok_emb[t * EMB + c] * w0cat(Wl0, Wr0, c, j);
    T[i] = s;
    return;
  }
  i -= S3;
  if (i < S4) {                              // F[r][j] = sum_b bbox_W[r][b] * W0cat(256+b, j)
    int r = i >> 8, j = i & 255;
    float s = 0.f;
#pragma unroll
    for (int b = 0; b < NBBOX; b++) s += bbox_W[r * NBBOX + b] * w0cat(Wl0, Wr0, EMB + b, j);
    F[i] = s;
    return;
  }
  i -= S4;
  if (i < S5) {                              // c[j] = sum_b bbox_b[b]*W0cat(256+b,j) + (bl0|br0)[j]
    int j = i;
    float s = (j < 128) ? bl0[j] : br0[j - 128];
#pragma unroll
    for (int b = 0; b < NBBOX; b++) s += bbox_b[b] * w0cat(Wl0, Wr0, EMB + b, j);
    cvec[j] = s;
  }
}

// ---------------- layer-0 transform: xlxr[n] = T[tok_id[n]] + bbox[n]@F + c (bf16 out) ----------------
__global__ void se_xform0(const int* __restrict__ tok_id, const float* __restrict__ bbox,
                          const float* __restrict__ T, const float* __restrict__ F,
                          const float* __restrict__ cvec, ushort* __restrict__ xlxr) {
  int idx = blockIdx.x * 256 + threadIdx.x;   // one uint4 = 8 channels
  if (idx >= N_NODES * 32) return;
  const int n = idx >> 5, k = idx & 31;
  const int j0 = k * 8;
  const int t = tok_id[n];
  const float4 bb = *(const float4*)(bbox + (size_t)n * 4);
  float o[8];
#pragma unroll
  for (int h = 0; h < 2; h++) {
    const float4 tv = *(const float4*)(T + t * 256 + j0 + 4 * h);
    const float4 cv = *(const float4*)(cvec + j0 + 4 * h);
    const float4 f0 = *(const float4*)(F + 0 * 256 + j0 + 4 * h);
    const float4 f1 = *(const float4*)(F + 1 * 256 + j0 + 4 * h);
    const float4 f2 = *(const float4*)(F + 2 * 256 + j0 + 4 * h);
    const float4 f3 = *(const float4*)(F + 3 * 256 + j0 + 4 * h);
    o[4 * h + 0] = tv.x + cv.x + bb.x * f0.x + bb.y * f1.x + bb.z * f2.x + bb.w * f3.x;
    o[4 * h + 1] = tv.y + cv.y + bb.x * f0.y + bb.y * f1.y + bb.z * f2.y + bb.w * f3.y;
    o[4 * h + 2] = tv.z + cv.z + bb.x * f0.z + bb.y * f1.z + bb.z * f2.z + bb.w * f3.z;
    o[4 * h + 3] = tv.w + cv.w + bb.x * f0.w + bb.y * f1.w + bb.z * f2.w + bb.w * f3.w;
  }
  uint4 p;
  p.x = ((uint)f2bf(o[1]) << 16) | f2bf(o[0]);
  p.y = ((uint)f2bf(o[3]) << 16) | f2bf(o[2]);
  p.z = ((uint)f2bf(o[5]) << 16) | f2bf(o[4]);
  p.w = ((uint)f2bf(o[7]) << 16) | f2bf(o[6]);
  ((uint4*)xlxr)[idx] = p;
}

// ---------------- CSR build (rows padded to multiples of 8, sentinel-filled) ----------------
__global__ void se_hist(const int* __restrict__ ei, int* __restrict__ deg) {
  int e = blockIdx.x * 256 + threadIdx.x;
  if (e < N_EDGES) atomicAdd(&deg[ei[N_EDGES + e]], 1);
}
__global__ __launch_bounds__(1024) void se_scanA(const int* __restrict__ deg,
                                                 int* __restrict__ offs, int* __restrict__ bsum) {
  __shared__ int s[1024];
  const int tid = threadIdx.x;
  const int i = blockIdx.x * 1024 + tid;
  int v = (i < N_NODES) ? ((deg[i] + 7) & ~7) : 0;   // padded degree (x8)
  s[tid] = v;
  __syncthreads();
  for (int d = 1; d < 1024; d <<= 1) {
    int t = (tid >= d) ? s[tid - d] : 0;
    __syncthreads();
    s[tid] += t;
    __syncthreads();
  }
  if (i < N_NODES) offs[i] = s[tid] - v;
  if (tid == 1023) bsum[blockIdx.x] = s[1023];
}
__global__ __launch_bounds__(128) void se_scanB(int* __restrict__ bsum, int nb) {
  __shared__ int s[128];
  const int t = threadIdx.x;
  int v = (t < nb) ? bsum[t] : 0;
  s[t] = v;
  __syncthreads();
  for (int d = 1; d < 128; d <<= 1) {
    int u = (t >= d) ? s[t - d] : 0;
    __syncthreads();
    s[t] += u;
    __syncthreads();
  }
  if (t < nb) bsum[t] = s[t] - v;   // exclusive
}
// fused scanC + padfill: finalize offs, emit rowinfo=(offs, nit8), sentinel-fill pads + guard
__global__ __launch_bounds__(1024) void se_scanC_pad(int* __restrict__ offs,
                                                     const int* __restrict__ bsum,
                                                     const int* __restrict__ deg,
                                                     uint* __restrict__ csrp,
                                                     int2* __restrict__ rowinfo) {
  int i = blockIdx.x * 1024 + threadIdx.x;
  if (i >= N_NODES) return;
  const int o = offs[i] + bsum[blockIdx.x];
  offs[i] = o;
  const int d = deg[i];
  rowinfo[i] = make_int2(o, (d + 7) >> 3);
  const int s = o + d;
  const int c = ((d + 7) & ~7) - d;
  for (int j = 0; j < c; j++) csrp[s + j] = SENT;
  if (i == N_NODES - 1) {
    const int e = o + ((d + 7) & ~7);
    for (int j = 0; j < 64; j++) csrp[e + j] = SENT;
  }
}
__global__ void se_scatter(const int* __restrict__ ei, const int* __restrict__ eattr,
                           const int* __restrict__ offs, int* __restrict__ cur,
                           uint* __restrict__ csrp) {
  int e = blockIdx.x * 256 + threadIdx.x;
  if (e < N_EDGES) {
    int d = ei[N_EDGES + e];
    int p = offs[d] + atomicAdd(&cur[d], 1);
    csrp[p] = (uint)ei[e] | ((uint)eattr[e] << 20);
  }
}

// ---------------- GEMM: C[N,256] = A[N,K] @ BT[256,K]^T + biascat, bf16 in/out, fp32 acc ----------------
template <int K>
__global__ __launch_bounds__(256) void se_gemm(const ushort* __restrict__ A,
                                               const ushort* __restrict__ BT,
                                               const float* __restrict__ bias,
                                               ushort* __restrict__ C) {
  __shared__ __align__(16) ushort As[128 * 32];
  __shared__ __align__(16) ushort Bs[128 * 32];
  const int tid = threadIdx.x;
  const int w = tid >> 6, l = tid & 63;
  const int wr = w >> 1, wc = w & 1;
  const int m0 = blockIdx.x * 128, n0 = blockIdx.y * 128;
  fx4 acc[4][4];
#pragma unroll
  for (int i = 0; i < 4; i++)
#pragma unroll
    for (int j = 0; j < 4; j++) acc[i][j] = fx4{0.f, 0.f, 0.f, 0.f};

  for (int k0 = 0; k0 < K; k0 += 32) {
#pragma unroll
    for (int ch = 0; ch < 2; ch++) {
      const int t = tid + ch * 256;          // 16B chunk id; row=t/4, col=(t%4)*8
      const int r = t >> 2, c = (t & 3) << 3;
      const ushort* ga = A + (size_t)(m0 + r) * K + (k0 + c);
      ushort* la = As + (size_t)(ch * 256 + w * 64) * 8;
      __builtin_amdgcn_global_load_lds((const __attribute__((address_space(1))) void*)ga,
                                       (__attribute__((address_space(3))) void*)la, 16, 0, 0);
      const ushort* gb = BT + (size_t)(n0 + r) * K + (k0 + c);
      ushort* lb = Bs + (size_t)(ch * 256 + w * 64) * 8;
      __builtin_amdgcn_global_load_lds((const __attribute__((address_space(1))) void*)gb,
                                       (__attribute__((address_space(3))) void*)lb, 16, 0, 0);
    }
    __syncthreads();
    bfx8 af[4], bfr[4];
#pragma unroll
    for (int i = 0; i < 4; i++) {
      af[i]  = *(const bfx8*)(As + ((wr * 64 + i * 16 + (l & 15)) * 32 + ((l >> 4) * 8)));
      bfr[i] = *(const bfx8*)(Bs + ((wc * 64 + i * 16 + (l & 15)) * 32 + ((l >> 4) * 8)));
    }
#pragma unroll
    for (int i = 0; i < 4; i++)
#pragma unroll
      for (int j = 0; j < 4; j++)
        acc[i][j] = __builtin_amdgcn_mfma_f32_16x16x32_bf16(af[i], bfr[j], acc[i][j], 0, 0, 0);
    __syncthreads();
  }
#pragma unroll
  for (int i = 0; i < 4; i++) {
    const int rbase = m0 + wr * 64 + i * 16 + ((l >> 4) << 2);
#pragma unroll
    for (int j = 0; j < 4; j++) {
      const int col = n0 + wc * 64 + j * 16 + (l & 15);
      const float bz = bias[col];
#pragma unroll
      for (int r2 = 0; r2 < 4; r2++) {
        const int row = rbase + r2;
        if (row < N_NODES) C[(size_t)row * 256 + col] = f2bf(acc[i][j][r2] + bz);
      }
    }
  }
}

// ---------------- GATv2 aggregation: 8 edges/wave (8 lanes = 1 head each), in-lane head dot ----------------
__global__ __launch_bounds__(256) void se_agg(const uint4* __restrict__ xlxr4,
                                              const uint* __restrict__ csrp,
                                              const int2* __restrict__ rowinfo,
                                              const float* __restrict__ eetab,
                                              const float* __restrict__ att,
                                              const float* __restrict__ bias,
                                              float* __restrict__ y, float* __restrict__ partial) {
  __shared__ ushort ee[64 * HID];         // bf16, rows >= NREL zeroed (sentinel), 16 KB
  __shared__ float bstat[256];
  const int tid = threadIdx.x, w = tid >> 6, l = tid & 63;
  const int g = l >> 3, j = l & 7;        // group (edge slot 0..7), head j (16 channels)
  for (int i = tid; i < 64 * HID; i += 256) {
    const int r = i >> 7;
    ee[i] = (r < NREL) ? f2bf(eetab[i]) : (ushort)0;
  }
  bstat[tid] = 0.f;
  __syncthreads();
  // att for head j, pre-scaled by log2(e); lrelu(m) = max(m, 0.2m)
  v2f av[8];
  {
    const float* ap = att + j * NCH;
#pragma unroll
    for (int q = 0; q < 8; q++) av[q] = v2f{ap[2 * q] * L2E, ap[2 * q + 1] * L2E};
  }
  v2f sv[8], qv[8];
#pragma unroll
  for (int q = 0; q < 8; q++) { sv[q] = v2f{0.f, 0.f}; qv[q] = v2f{0.f, 0.f}; }
  const v2f zero = v2f{0.f, 0.f};

  const int stride = gridDim.x * 4;
  for (int n = blockIdx.x * 4 + w; n < N_NODES; n += stride) {
    const int2 ri = rowinfo[n];
    const uint* rowp = csrp + ri.x + g;
    const int nit = ri.y;                 // wave-uniform -> scalar guards below
    v2f xrv[8];
    {
      const uint b = (uint)n * 32u + 16u + (uint)(j * 2);
      const uint4 x0 = xlxr4[b], x1 = xlxr4[b + 1u];
      xrv[0] = up2(x0.x); xrv[1] = up2(x0.y); xrv[2] = up2(x0.z); xrv[3] = up2(x0.w);
      xrv[4] = up2(x1.x); xrv[5] = up2(x1.y); xrv[6] = up2(x1.z); xrv[7] = up2(x1.w);
    }
    float den = 0.f;
    v2f acc[8];
#pragma unroll
    for (int q = 0; q < 8; q++) acc[q] = zero;

    uint eA = SENT, eB = SENT;
    uint4 xa0 = uint4{0u, 0u, 0u, 0u}, xa1 = uint4{0u, 0u, 0u, 0u};
    if (nit > 0) {
      eA = rowp[0];
      const uint s0 = (eA & 0xFFFFFu) * 32u + (uint)(j * 2);
      xa0 = xlxr4[s0]; xa1 = xlxr4[s0 + 1u];
      if (nit > 1) eB = rowp[8];
    }
    for (int i = 0; i < nit; ++i) {
      const uint ec = eA;
      const uint4 xc0 = xa0, xc1 = xa1;
      eA = eB;
      if (i + 1 < nit) {                                      // gather for i+1
        const uint s1 = (eA & 0xFFFFFu) * 32u + (uint)(j * 2);
        xa0 = xlxr4[s1]; xa1 = xlxr4[s1 + 1u];
      }
      if (i + 2 < nit) eB = rowp[8 * (i + 2)];                // csr for i+2
      const ushort* eerow = ee + (ec >> 20) * HID + j * 16;
      const uint4 eu0 = *(const uint4*)(eerow);
      const uint4 eu1 = *(const uint4*)(eerow + 8);
      v2f sd = zero;
      v2f xls[8];
      {
        const uint xcu[8] = {xc0.x, xc0.y, xc0.z, xc0.w, xc1.x, xc1.y, xc1.z, xc1.w};
        const uint eu[8]  = {eu0.x, eu0.y, eu0.z, eu0.w, eu1.x, eu1.y, eu1.z, eu1.w};
#pragma unroll
        for (int q = 0; q < 8; q++) {
          const v2f xl = up2(xcu[q]);
          const v2f m = xl + xrv[q] + up2(eu[q]);
          const v2f lk = __builtin_elementwise_max(m, NEG_SLOPE * m);
          sd += lk * av[q];
          xls[q] = xl;
        }
      }
      float s = sd.x + sd.y;               // full 16-ch head dot, in-lane (no shfl)
      s = (ec >= SENT_MIN) ? -1e30f : s;   // sentinel -> p = 0
      const float p = exp2f(s);
      den += p;
      const v2f pp = v2f{p, p};
#pragma unroll
      for (int q = 0; q < 8; q++) acc[q] += pp * xls[q];
    }
    // combine 8 edge-groups (global exp domain, plain sums)
#pragma unroll
    for (int lvl = 8; lvl <= 32; lvl <<= 1) {
      den += __shfl_xor(den, lvl);
#pragma unroll
      for (int q = 0; q < 8; q++) {
        acc[q].x += __shfl_xor(acc[q].x, lvl);
        acc[q].y += __shfl_xor(acc[q].y, lvl);
      }
    }
    if (g == 0) {
      const float r = 1.f / fmaxf(den, 1e-16f);
      const v2f rr = v2f{r, r};
      const float* bp = bias + j * 16;
      v2f ov[8];
#pragma unroll
      for (int q = 0; q < 8; q++) {
        ov[q] = __builtin_elementwise_max(acc[q] * rr + v2f{bp[2 * q], bp[2 * q + 1]}, zero);
        sv[q] += ov[q];
        qv[q] += ov[q] * ov[q];
      }
      float4* yp = (float4*)(y + (size_t)n * HID + j * 16);
      yp[0] = make_float4(ov[0].x, ov[0].y, ov[1].x, ov[1].y);
      yp[1] = make_float4(ov[2].x, ov[2].y, ov[3].x, ov[3].y);
      yp[2] = make_float4(ov[4].x, ov[4].y, ov[5].x, ov[5].y);
      yp[3] = make_float4(ov[6].x, ov[6].y, ov[7].x, ov[7].y);
    }
  }
  if (l < 8) {
#pragma unroll
    for (int q = 0; q < 8; q++) {
      unsafeAtomicAdd(&bstat[j * 16 + 2 * q], sv[q].x);
      unsafeAtomicAdd(&bstat[j * 16 + 2 * q + 1], sv[q].y);
      unsafeAtomicAdd(&bstat[128 + j * 16 + 2 * q], qv[q].x);
      unsafeAtomicAdd(&bstat[128 + j * 16 + 2 * q + 1], qv[q].y);
    }
  }
  __syncthreads();
  partial[(size_t)tid * AGG_BLOCKS + blockIdx.x] = bstat[tid];
}

// ---------------- BN stats finalize: mean + rsqrt(var+eps) per channel ----------------
__global__ __launch_bounds__(256) void se_stats(const float* __restrict__ partial, float* __restrict__ musig) {
  __shared__ float red[256];
  const int ch = blockIdx.x, tid = threadIdx.x;
  float s = 0.f;
  for (int i = tid; i < AGG_BLOCKS; i += 256) s += partial[ch * AGG_BLOCKS + i];
  red[tid] = s; __syncthreads();
  for (int o = 128; o > 0; o >>= 1) { if (tid < o) red[tid] += red[tid + o]; __syncthreads(); }
  const float sum = red[0]; __syncthreads();
  float q = 0.f;
  for (int i = tid; i < AGG_BLOCKS; i += 256) q += partial[(128 + ch) * AGG_BLOCKS + i];
  red[tid] = q; __syncthreads();
  for (int o = 128; o > 0; o >>= 1) { if (tid < o) red[tid] += red[tid + o]; __syncthreads(); }
  if (tid == 0) {
    const float mean = sum / (float)N_NODES;
    const float var = red[0] / (float)N_NODES - mean * mean;
    musig[ch] = mean;
    musig[128 + ch] = rsqrtf(var + EPS_BN);
  }
}

// ---------------- BN apply (+ bf16 residual), y fp32 in; h bf16 in/out ----------------
__global__ void se_bn(const float* __restrict__ y, const float* __restrict__ musig,
                      const float* __restrict__ gamma, const float* __restrict__ beta,
                      ushort* __restrict__ h_bf, int residual) {
  int idx = blockIdx.x * 256 + threadIdx.x;     // one uint4 = 8 channels
  if (idx >= N_NODES * 16) return;
  const int k = idx & 15;                       // ch = k*8
  const float4 y0 = ((const float4*)y)[(size_t)idx * 2];
  const float4 y1 = ((const float4*)y)[(size_t)idx * 2 + 1];
  const float4 mu0 = ((const float4*)musig)[k * 2],         mu1 = ((const float4*)musig)[k * 2 + 1];
  const float4 rs0 = ((const float4*)(musig + 128))[k * 2], rs1 = ((const float4*)(musig + 128))[k * 2 + 1];
  const float4 g0  = ((const float4*)gamma)[k * 2],         g1  = ((const float4*)gamma)[k * 2 + 1];
  const float4 b0  = ((const float4*)beta)[k * 2],          b1  = ((const float4*)beta)[k * 2 + 1];
  float v[8];
  v[0] = g0.x * (y0.x - mu0.x) * rs0.x + b0.x;
  v[1] = g0.y * (y0.y - mu0.y) * rs0.y + b0.y;
  v[2] = g0.z * (y0.z - mu0.z) * rs0.z + b0.z;
  v[3] = g0.w * (y0.w - mu0.w) * rs0.w + b0.w;
  v[4] = g1.x * (y1.x - mu1.x) * rs1.x + b1.x;
  v[5] = g1.y * (y1.y - mu1.y) * rs1.y + b1.y;
  v[6] = g1.z * (y1.z - mu1.z) * rs1.z + b1.z;
  v[7] = g1.w * (y1.w - mu1.w) * rs1.w + b1.w;
  if (residual) {
    const uint4 ho = ((const uint4*)h_bf)[idx];
    float fr[8];
    unpack8(ho, fr);
#pragma unroll
    for (int j = 0; j < 8; j++) v[j] += fr[j];
  }
  uint4 p4;
  p4.x = ((uint)f2bf(v[1]) << 16) | f2bf(v[0]);
  p4.y = ((uint)f2bf(v[3]) << 16) | f2bf(v[2]);
  p4.z = ((uint)f2bf(v[5]) << 16) | f2bf(v[4]);
  p4.w = ((uint)f2bf(v[7]) << 16) | f2bf(v[6]);
  ((uint4*)h_bf)[idx] = p4;
}

// ---------------- mean pool: run-length register accumulation (batch sorted), global-atomic flush ----------------
__global__ __launch_bounds__(256) void se_pool(const ushort* __restrict__ h_bf,
                                               const int* __restrict__ batch,
                                               float* __restrict__ pool) {
  const int tid = threadIdx.x, w = tid >> 6, l = tid & 63;
  const int wid = blockIdx.x * 4 + w;
  const int nw = gridDim.x * 4;
  const int chunk = (N_NODES + nw - 1) / nw;
  const int start = wid * chunk;
  const int end = min(N_NODES, start + chunk);
  float a0 = 0.f, a1 = 0.f;
  int cg = -1, cnt = 0;
  for (int n = start; n < end; ++n) {
    const int gg = batch[n];
    if (gg != cg) {
      if (cg >= 0) {
        unsafeAtomicAdd(&pool[cg * HID + 2 * l], a0);
        unsafeAtomicAdd(&pool[cg * HID + 2 * l + 1], a1);
        if (l == 0) unsafeAtomicAdd(&pool[NGRAPH * HID + cg], (float)cnt);
      }
      a0 = 0.f; a1 = 0.f; cnt = 0; cg = gg;
    }
    const uint u = ((const uint*)h_bf)[(size_t)n * 64 + l];
    a0 += bf2f(u & 0xffffu);
    a1 += __uint_as_float(u & 0xffff0000u);
    cnt++;
  }
  if (cg >= 0) {
    unsafeAtomicAdd(&pool[cg * HID + 2 * l], a0);
    unsafeAtomicAdd(&pool[cg * HID + 2 * l + 1], a1);
    if (l == 0) unsafeAtomicAdd(&pool[NGRAPH * HID + cg], (float)cnt);
  }
}
__global__ void se_poolfin(const float* __restrict__ pool, float* __restrict__ out) {
  int idx = blockIdx.x * 256 + threadIdx.x;
  if (idx < NGRAPH * HID) {
    int g = idx >> 7;
    out[idx] = pool[idx] / fmaxf(pool[NGRAPH * HID + g], 1.f);
  }
}

extern "C" void kernel_launch(void* const* d_in, const int* in_sizes, int n_in,
                              void* d_out, int out_size, void* d_ws, size_t ws_size,
                              hipStream_t stream) {
  (void)in_sizes; (void)n_in; (void)out_size; (void)ws_size;
  const int*   tok_id  = (const int*)d_in[0];
  const float* bbox    = (const float*)d_in[1];
  const int*   ei      = (const int*)d_in[2];
  const int*   eattr   = (const int*)d_in[3];
  const int*   batch   = (const int*)d_in[4];
  const float* tok_emb = (const float*)d_in[5];
  const float* bbox_W  = (const float*)d_in[6];
  const float* bbox_b  = (const float*)d_in[7];
  const float* rel_emb = (const float*)d_in[8];
  const float* Wl0  = (const float*)d_in[9];
  const float* bl0  = (const float*)d_in[10];
  const float* Wr0  = (const float*)d_in[11];
  const float* br0  = (const float*)d_in[12];
  const float* We0  = (const float*)d_in[13];
  const float* att0 = (const float*)d_in[14];
  const float* bias0  = (const float*)d_in[15];
  const float* gamma0 = (const float*)d_in[16];
  const float* beta0  = (const float*)d_in[17];
  const float* WlS  = (const float*)d_in[18];
  const float* blS  = (const float*)d_in[19];
  const float* WrS  = (const float*)d_in[20];
  const float* brS  = (const float*)d_in[21];
  const float* WeS  = (const float*)d_in[22];
  const float* attS = (const float*)d_in[23];
  const float* biasS  = (const float*)d_in[24];
  const float* gammaS = (const float*)d_in[25];
  const float* betaS  = (const float*)d_in[26];
  float* out = (float*)d_out;

  char* ws = (char*)d_ws;
  size_t off = 0;
  auto alloc = [&](size_t bytes) -> char* {
    char* p = ws + off;
    off = (off + bytes + 255) & ~(size_t)255;
    return p;
  };
  ushort* xlxr = (ushort*)alloc((size_t)N_PAD * 256 * 2);
  float*  y    = (float*)alloc((size_t)N_NODES * HID * 4);
  ushort* h_bf = (ushort*)alloc((size_t)N_PAD * HID * 2);
  ushort* WST  = (ushort*)alloc((size_t)2 * 256 * HID * 2);
  float*  eetab   = (float*)alloc((size_t)3 * NREL * HID * 4);
  float*  biascat = (float*)alloc((size_t)3 * 256 * 4);
  float*  T    = (float*)alloc((size_t)NTOK * 256 * 4);
  float*  F    = (float*)alloc((size_t)4 * 256 * 4);
  float*  cvec = (float*)alloc((size_t)256 * 4);
  // deg | cur | pool contiguous -> single memset
  char*  z0   = ws + off;
  int*   deg  = (int*)alloc((size_t)N_NODES * 4);
  int*   cur  = (int*)alloc((size_t)N_NODES * 4);
  float* pool = (float*)alloc((size_t)(NGRAPH * HID + NGRAPH) * 4);
  size_t zlen = (size_t)((ws + off) - z0);
  int* offs = (int*)alloc((size_t)(N_NODES + 1) * 4);
  int* bsum = (int*)alloc(128 * 4);
  int2* rowinfo = (int2*)alloc((size_t)N_NODES * 8);
  uint* csrp = (uint*)alloc((size_t)(N_EDGES + 7 * N_NODES + 256) * 4);
  float* partial = (float*)alloc((size_t)256 * AGG_BLOCKS * 4);
  float* musig   = (float*)alloc(256 * 4);

  hipMemsetAsync(z0, 0, zlen, stream);

  se_prep<<<(PREP_TOT + 255) / 256, 256, 0, stream>>>(
      Wl0, Wr0, WlS, WrS, rel_emb, We0, WeS, bl0, br0, blS, brS,
      tok_emb, bbox_W, bbox_b, WST, eetab, biascat, T, F, cvec);
  se_hist<<<(N_EDGES + 255) / 256, 256, 0, stream>>>(ei, deg);
  se_scanA<<<98, 1024, 0, stream>>>(deg, offs, bsum);
  se_scanB<<<1, 128, 0, stream>>>(bsum, 98);
  se_scanC_pad<<<98, 1024, 0, stream>>>(offs, bsum, deg, csrp, rowinfo);
  se_scatter<<<(N_EDGES + 255) / 256, 256, 0, stream>>>(ei, eattr, offs, cur, csrp);

  // layer 0: folded transform (replaces build_x + K=288 GEMM)
  se_xform0<<<(N_NODES * 32 + 255) / 256, 256, 0, stream>>>(tok_id, bbox, T, F, cvec, xlxr);
  se_agg<<<AGG_BLOCKS, 256, 0, stream>>>((const uint4*)xlxr, csrp, rowinfo,
                                         eetab, att0, bias0, y, partial);
  se_stats<<<128, 256, 0, stream>>>(partial, musig);
  se_bn<<<(N_NODES * 16 + 255) / 256, 256, 0, stream>>>(y, musig, gamma0, beta0, h_bf, 0);

  // layers 1..2 (K=128)
  for (int li = 0; li < 2; ++li) {
    se_gemm<HID><<<dim3(N_PAD / 128, 2), 256, 0, stream>>>(h_bf, WST + (size_t)li * 256 * HID,
                                                           biascat + (li + 1) * 256, xlxr);
    se_agg<<<AGG_BLOCKS, 256, 0, stream>>>((const uint4*)xlxr, csrp, rowinfo,
                                           eetab + (size_t)(li + 1) * NREL * HID,
                                           attS + (size_t)li * NHEAD * NCH,
                                           biasS + (size_t)li * HID, y, partial);
    se_stats<<<128, 256, 0, stream>>>(partial, musig);
    se_bn<<<(N_NODES * 16 + 255) / 256, 256, 0, stream>>>(y, musig, gammaS + (size_t)li * HID,
                                                          betaS + (size_t)li * HID, h_bf, 1);
  }

  se_pool<<<POOL_BLOCKS, 256, 0, stream>>>(h_bf, batch, pool);
  se_poolfin<<<32, 256, 0, stream>>>(pool, out);
}

// Round 10
// 810.721 us; speedup vs baseline: 1.1153x; 1.1153x over previous
//
#include <hip/hip_runtime.h>

#define N_NODES 100000
#define N_PAD   100096
#define N_EDGES 1600000
#define NGRAPH  64
#define NHEAD   8
#define NCH     16
#define HID     128
#define IN0     288
#define NREL    51
#define EMB     256
#define NBBOX   32
#define NTOK    151
#define NEG_SLOPE 0.2f
#define EPS_BN  1e-5f
#define AGG_BLOCKS 2048
#define POOL_BLOCKS 1024
#define SENT 0x03F00000u          /* rel=63, src=0 */
#define SENT_MIN ((uint)(NREL) << 20)
#define L2E 1.4426950408889634f

typedef unsigned int uint;
typedef unsigned short ushort;

typedef __bf16 bf16_t;
typedef bf16_t bfx8 __attribute__((ext_vector_type(8)));
typedef float  fx4  __attribute__((ext_vector_type(4)));
typedef float  v2f  __attribute__((ext_vector_type(2)));

__device__ __forceinline__ ushort f2bf(float f) {
  uint u = __float_as_uint(f);
  u += 0x7fffu + ((u >> 16) & 1u);
  return (ushort)(u >> 16);
}
__device__ __forceinline__ float bf2f(uint u) { return __uint_as_float(u << 16); }
__device__ __forceinline__ v2f up2(uint u) {
  v2f r;
  r.x = __uint_as_float(u << 16);
  r.y = __uint_as_float(u & 0xffff0000u);
  return r;
}
__device__ __forceinline__ void unpack8(uint4 u, float* f) {
  f[0] = __uint_as_float(u.x << 16); f[1] = __uint_as_float(u.x & 0xffff0000u);
  f[2] = __uint_as_float(u.y << 16); f[3] = __uint_as_float(u.y & 0xffff0000u);
  f[4] = __uint_as_float(u.z << 16); f[5] = __uint_as_float(u.z & 0xffff0000u);
  f[6] = __uint_as_float(u.w << 16); f[7] = __uint_as_float(u.w & 0xffff0000u);
}

// W0cat(c, j): j<128 -> Wl0[c][j], j>=128 -> Wr0[c][j-128]
__device__ __forceinline__ float w0cat(const float* Wl0, const float* Wr0, int c, int j) {
  return (j < 128) ? Wl0[c * 128 + j] : Wr0[c * 128 + (j - 128)];
}

// ---------------- prep: WST transpose->bf16, ee tables, biascat, layer-0 folded tables T/F/c ----------------
#define S0 (2 * 256 * HID)
#define S1 (3 * NREL * HID)
#define S2 (3 * 256)
#define S3 (NTOK * 256)
#define S4 (4 * 256)
#define S5 (256)
#define PREP_TOT (S0 + S1 + S2 + S3 + S4 + S5)
__global__ void se_prep(const float* __restrict__ Wl0, const float* __restrict__ Wr0,
                        const float* __restrict__ WlS, const float* __restrict__ WrS,
                        const float* __restrict__ rel_emb, const float* __restrict__ We0,
                        const float* __restrict__ WeS,
                        const float* __restrict__ bl0, const float* __restrict__ br0,
                        const float* __restrict__ blS, const float* __restrict__ brS,
                        const float* __restrict__ tok_emb, const float* __restrict__ bbox_W,
                        const float* __restrict__ bbox_b,
                        ushort* __restrict__ WST, float* __restrict__ eetab,
                        float* __restrict__ biascat,
                        float* __restrict__ T, float* __restrict__ F, float* __restrict__ cvec) {
  int i = blockIdx.x * 256 + threadIdx.x;
  if (i < S0) {                              // WST[l][j][k] = (Wl|Wr)S[l][k][j] as bf16
    int li = i >> 15;
    int rem = i & 32767;
    int j = rem >> 7, k = rem & 127;
    float v = (j < 128) ? WlS[(li * 128 + k) * 128 + j] : WrS[(li * 128 + k) * 128 + (j - 128)];
    WST[(li * 256 + j) * 128 + k] = f2bf(v);
    return;
  }
  i -= S0;
  if (i < S1) {                              // eetab[l][r][j] = sum_c rel[r][c]*We_l[c][j]
    int li = i / (NREL * HID);
    int rem = i - li * (NREL * HID);
    int r = rem >> 7, j = rem & 127;
    const float* We = (li == 0) ? We0 : (WeS + (li - 1) * NCH * HID);
    float s = 0.f;
#pragma unroll
    for (int c = 0; c < NCH; c++) s += rel_emb[r * NCH + c] * We[c * HID + j];
    eetab[li * (NREL * HID) + rem] = s;
    return;
  }
  i -= S1;
  if (i < S2) {                              // biascat[l][256] = bl|br
    int li = i >> 8, j = i & 255;
    const float* bl = (li == 0) ? bl0 : (blS + (li - 1) * HID);
    const float* br = (li == 0) ? br0 : (brS + (li - 1) * HID);
    biascat[i] = (j < 128) ? bl[j] : br[j - 128];
    return;
  }
  i -= S2;
  if (i < S3) {                              // T[t][j] = sum_c tok_emb[t][c] * W0cat(c, j)
    int t = i >> 8, j = i & 255;
    float s = 0.f;
    for (int c = 0; c < EMB; c++) s += tok_emb[t * EMB + c] * w0cat(Wl0, Wr0, c, j);
    T[i] = s;
    return;
  }
  i -= S3;
  if (i < S4) {                              // F[r][j] = sum_b bbox_W[r][b] * W0cat(256+b, j)
    int r = i >> 8, j = i & 255;
    float s = 0.f;
#pragma unroll
    for (int b = 0; b < NBBOX; b++) s += bbox_W[r * NBBOX + b] * w0cat(Wl0, Wr0, EMB + b, j);
    F[i] = s;
    return;
  }
  i -= S4;
  if (i < S5) {                              // c[j] = sum_b bbox_b[b]*W0cat(256+b,j) + (bl0|br0)[j]
    int j = i;
    float s = (j < 128) ? bl0[j] : br0[j - 128];
#pragma unroll
    for (int b = 0; b < NBBOX; b++) s += bbox_b[b] * w0cat(Wl0, Wr0, EMB + b, j);
    cvec[j] = s;
  }
}

// ---------------- layer-0 transform: xlxr[n] = T[tok_id[n]] + bbox[n]@F + c (bf16 out) ----------------
__global__ void se_xform0(const int* __restrict__ tok_id, const float* __restrict__ bbox,
                          const float* __restrict__ T, const float* __restrict__ F,
                          const float* __restrict__ cvec, ushort* __restrict__ xlxr) {
  int idx = blockIdx.x * 256 + threadIdx.x;   // one uint4 = 8 channels
  if (idx >= N_NODES * 32) return;
  const int n = idx >> 5, k = idx & 31;
  const int j0 = k * 8;
  const int t = tok_id[n];
  const float4 bb = *(const float4*)(bbox + (size_t)n * 4);
  float o[8];
#pragma unroll
  for (int h = 0; h < 2; h++) {
    const float4 tv = *(const float4*)(T + t * 256 + j0 + 4 * h);
    const float4 cv = *(const float4*)(cvec + j0 + 4 * h);
    const float4 f0 = *(const float4*)(F + 0 * 256 + j0 + 4 * h);
    const float4 f1 = *(const float4*)(F + 1 * 256 + j0 + 4 * h);
    const float4 f2 = *(const float4*)(F + 2 * 256 + j0 + 4 * h);
    const float4 f3 = *(const float4*)(F + 3 * 256 + j0 + 4 * h);
    o[4 * h + 0] = tv.x + cv.x + bb.x * f0.x + bb.y * f1.x + bb.z * f2.x + bb.w * f3.x;
    o[4 * h + 1] = tv.y + cv.y + bb.x * f0.y + bb.y * f1.y + bb.z * f2.y + bb.w * f3.y;
    o[4 * h + 2] = tv.z + cv.z + bb.x * f0.z + bb.y * f1.z + bb.z * f2.z + bb.w * f3.z;
    o[4 * h + 3] = tv.w + cv.w + bb.x * f0.w + bb.y * f1.w + bb.z * f2.w + bb.w * f3.w;
  }
  uint4 p;
  p.x = ((uint)f2bf(o[1]) << 16) | f2bf(o[0]);
  p.y = ((uint)f2bf(o[3]) << 16) | f2bf(o[2]);
  p.z = ((uint)f2bf(o[5]) << 16) | f2bf(o[4]);
  p.w = ((uint)f2bf(o[7]) << 16) | f2bf(o[6]);
  ((uint4*)xlxr)[idx] = p;
}

// ---------------- CSR build (rows padded to multiples of 4, sentinel-filled) ----------------
__global__ void se_hist(const int* __restrict__ ei, int* __restrict__ deg) {
  int e = blockIdx.x * 256 + threadIdx.x;
  if (e < N_EDGES) atomicAdd(&deg[ei[N_EDGES + e]], 1);
}
__global__ __launch_bounds__(1024) void se_scanA(const int* __restrict__ deg,
                                                 int* __restrict__ offs, int* __restrict__ bsum) {
  __shared__ int s[1024];
  const int tid = threadIdx.x;
  const int i = blockIdx.x * 1024 + tid;
  int v = (i < N_NODES) ? ((deg[i] + 3) & ~3) : 0;   // padded degree (x4)
  s[tid] = v;
  __syncthreads();
  for (int d = 1; d < 1024; d <<= 1) {
    int t = (tid >= d) ? s[tid - d] : 0;
    __syncthreads();
    s[tid] += t;
    __syncthreads();
  }
  if (i < N_NODES) offs[i] = s[tid] - v;
  if (tid == 1023) bsum[blockIdx.x] = s[1023];
}
__global__ __launch_bounds__(128) void se_scanB(int* __restrict__ bsum, int nb) {
  __shared__ int s[128];
  const int t = threadIdx.x;
  int v = (t < nb) ? bsum[t] : 0;
  s[t] = v;
  __syncthreads();
  for (int d = 1; d < 128; d <<= 1) {
    int u = (t >= d) ? s[t - d] : 0;
    __syncthreads();
    s[t] += u;
    __syncthreads();
  }
  if (t < nb) bsum[t] = s[t] - v;   // exclusive
}
// fused scanC + padfill: finalize offs, emit rowinfo=(offs, nit4), sentinel-fill pads + guard
__global__ __launch_bounds__(1024) void se_scanC_pad(int* __restrict__ offs,
                                                     const int* __restrict__ bsum,
                                                     const int* __restrict__ deg,
                                                     uint* __restrict__ csrp,
                                                     int2* __restrict__ rowinfo) {
  int i = blockIdx.x * 1024 + threadIdx.x;
  if (i >= N_NODES) return;
  const int o = offs[i] + bsum[blockIdx.x];
  offs[i] = o;
  const int d = deg[i];
  rowinfo[i] = make_int2(o, (d + 3) >> 2);
  const int s = o + d;
  const int c = ((d + 3) & ~3) - d;
  for (int j = 0; j < c; j++) csrp[s + j] = SENT;
  if (i == N_NODES - 1) {
    const int e = o + ((d + 3) & ~3);
    for (int j = 0; j < 64; j++) csrp[e + j] = SENT;
  }
}
__global__ void se_scatter(const int* __restrict__ ei, const int* __restrict__ eattr,
                           const int* __restrict__ offs, int* __restrict__ cur,
                           uint* __restrict__ csrp) {
  int e = blockIdx.x * 256 + threadIdx.x;
  if (e < N_EDGES) {
    int d = ei[N_EDGES + e];
    int p = offs[d] + atomicAdd(&cur[d], 1);
    csrp[p] = (uint)ei[e] | ((uint)eattr[e] << 20);
  }
}

// ---------------- GEMM: C[N,256] = A[N,K] @ BT[256,K]^T + biascat, bf16 in/out, fp32 acc ----------------
template <int K>
__global__ __launch_bounds__(256) void se_gemm(const ushort* __restrict__ A,
                                               const ushort* __restrict__ BT,
                                               const float* __restrict__ bias,
                                               ushort* __restrict__ C) {
  __shared__ __align__(16) ushort As[128 * 32];
  __shared__ __align__(16) ushort Bs[128 * 32];
  const int tid = threadIdx.x;
  const int w = tid >> 6, l = tid & 63;
  const int wr = w >> 1, wc = w & 1;
  const int m0 = blockIdx.x * 128, n0 = blockIdx.y * 128;
  fx4 acc[4][4];
#pragma unroll
  for (int i = 0; i < 4; i++)
#pragma unroll
    for (int j = 0; j < 4; j++) acc[i][j] = fx4{0.f, 0.f, 0.f, 0.f};

  for (int k0 = 0; k0 < K; k0 += 32) {
#pragma unroll
    for (int ch = 0; ch < 2; ch++) {
      const int t = tid + ch * 256;          // 16B chunk id; row=t/4, col=(t%4)*8
      const int r = t >> 2, c = (t & 3) << 3;
      const ushort* ga = A + (size_t)(m0 + r) * K + (k0 + c);
      ushort* la = As + (size_t)(ch * 256 + w * 64) * 8;
      __builtin_amdgcn_global_load_lds((const __attribute__((address_space(1))) void*)ga,
                                       (__attribute__((address_space(3))) void*)la, 16, 0, 0);
      const ushort* gb = BT + (size_t)(n0 + r) * K + (k0 + c);
      ushort* lb = Bs + (size_t)(ch * 256 + w * 64) * 8;
      __builtin_amdgcn_global_load_lds((const __attribute__((address_space(1))) void*)gb,
                                       (__attribute__((address_space(3))) void*)lb, 16, 0, 0);
    }
    __syncthreads();
    bfx8 af[4], bfr[4];
#pragma unroll
    for (int i = 0; i < 4; i++) {
      af[i]  = *(const bfx8*)(As + ((wr * 64 + i * 16 + (l & 15)) * 32 + ((l >> 4) * 8)));
      bfr[i] = *(const bfx8*)(Bs + ((wc * 64 + i * 16 + (l & 15)) * 32 + ((l >> 4) * 8)));
    }
#pragma unroll
    for (int i = 0; i < 4; i++)
#pragma unroll
      for (int j = 0; j < 4; j++)
        acc[i][j] = __builtin_amdgcn_mfma_f32_16x16x32_bf16(af[i], bfr[j], acc[i][j], 0, 0, 0);
    __syncthreads();
  }
#pragma unroll
  for (int i = 0; i < 4; i++) {
    const int rbase = m0 + wr * 64 + i * 16 + ((l >> 4) << 2);
#pragma unroll
    for (int j = 0; j < 4; j++) {
      const int col = n0 + wc * 64 + j * 16 + (l & 15);
      const float bz = bias[col];
#pragma unroll
      for (int r2 = 0; r2 < 4; r2++) {
        const int row = rbase + r2;
        if (row < N_NODES) C[(size_t)row * 256 + col] = f2bf(acc[i][j][r2] + bz);
      }
    }
  }
}

// ---------------- GATv2 aggregation: 4 edges/wave, node-level software pipeline ----------------
// Per-node serial chain (rowinfo -> csr -> gather) is issued one node ahead:
//   top of node n: issue rowinfo[n+stride]
//   after edge loop: issue csr e0(n+stride)   (rowinfo arrived during loop)
//   after combine:   issue gather x0(n+stride) (e0 arrived during combine)
__global__ __launch_bounds__(256) void se_agg(const uint4* __restrict__ xlxr4,
                                              const uint* __restrict__ csrp,
                                              const int2* __restrict__ rowinfo,
                                              const float* __restrict__ eetab,
                                              const float* __restrict__ att,
                                              const float* __restrict__ bias,
                                              float* __restrict__ y, float* __restrict__ partial) {
  __shared__ ushort ee[64 * HID];         // bf16, rows >= NREL zeroed (sentinel), 16 KB
  __shared__ float bstat[256];
  const int tid = threadIdx.x, w = tid >> 6, l = tid & 63;
  const int g = l >> 4, k = l & 15;       // group (edge slot), lane-in-group (8 channels)
  for (int i = tid; i < 64 * HID; i += 256) {
    const int r = i >> 7;
    ee[i] = (r < NREL) ? f2bf(eetab[i]) : (ushort)0;
  }
  bstat[tid] = 0.f;
  __syncthreads();
  // att pre-scaled by log2(e); lrelu(m) = max(m, 0.2m)
  v2f av[4];
  {
    const float* ap = att + (k >> 1) * NCH + (k & 1) * 8;
#pragma unroll
    for (int q = 0; q < 4; q++) av[q] = v2f{ap[2 * q] * L2E, ap[2 * q + 1] * L2E};
  }
  v2f sv[4], qv[4];
#pragma unroll
  for (int q = 0; q < 4; q++) { sv[q] = v2f{0.f, 0.f}; qv[q] = v2f{0.f, 0.f}; }
  const v2f zero = v2f{0.f, 0.f};

  const int stride = gridDim.x * 4;
  int n = blockIdx.x * 4 + w;
  // pipeline prologue for first node
  int2 ri = make_int2(0, 0);
  uint eA = SENT;
  uint4 xlv = uint4{0u, 0u, 0u, 0u};
  if (n < N_NODES) {
    ri = rowinfo[n];
    eA = csrp[ri.x + g];
    xlv = xlxr4[(eA & 0xFFFFFu) * 32u + (uint)k];
  }
  while (n < N_NODES) {
    const int n2 = n + stride;
    int2 ri2 = make_int2(0, 0);
    if (n2 < N_NODES) ri2 = rowinfo[n2];                     // issue 1 node ahead
    const uint4 xru = xlxr4[(uint)n * 32u + 16u + (uint)k];  // current xr
    const uint* rowp = csrp + ri.x + g;
    const int nit = ri.y;                 // wave-uniform -> scalar guards below
    uint eB = SENT;
    if (nit > 1) eB = rowp[4];
    v2f xrv[4];
    xrv[0] = up2(xru.x); xrv[1] = up2(xru.y); xrv[2] = up2(xru.z); xrv[3] = up2(xru.w);
    float den = 0.f;
    v2f acc[4];
#pragma unroll
    for (int q = 0; q < 4; q++) acc[q] = zero;

    for (int i = 0; i < nit; ++i) {
      const uint ec = eA;
      const uint4 xc = xlv;
      eA = eB;
      if (i + 1 < nit) xlv = xlxr4[(eA & 0xFFFFFu) * 32u + (uint)k];   // gather for i+1
      if (i + 2 < nit) eB = rowp[4 * (i + 2)];                         // csr for i+2
      const uint4 eeu = *(const uint4*)(ee + (ec >> 20) * HID + k * 8);
      v2f sd = zero;
      v2f xls[4];
      {
        const uint xcu[4] = {xc.x, xc.y, xc.z, xc.w};
        const uint eu[4] = {eeu.x, eeu.y, eeu.z, eeu.w};
#pragma unroll
        for (int q = 0; q < 4; q++) {
          const v2f xl = up2(xcu[q]);
          const v2f m = xl + xrv[q] + up2(eu[q]);
          const v2f lk = __builtin_elementwise_max(m, NEG_SLOPE * m);
          sd += lk * av[q];
          xls[q] = xl;
        }
      }
      float s = sd.x + sd.y;
      s += __shfl_xor(s, 1);               // full 16-ch head dot across lane pair
      s = (ec >= SENT_MIN) ? -1e30f : s;   // sentinel -> p = 0
      const float p = exp2f(s);
      den += p;
      const v2f pp = v2f{p, p};
#pragma unroll
      for (int q = 0; q < 4; q++) acc[q] += pp * xls[q];
    }
    // issue next node's first csr word (ri2 arrived during the edge loop)
    uint eA2 = SENT;
    if (n2 < N_NODES) eA2 = csrp[ri2.x + g];
    // combine groups (covers eA2 latency)
    den += __shfl_xor(den, 16);
    den += __shfl_xor(den, 32);
#pragma unroll
    for (int q = 0; q < 4; q++) {
      acc[q].x += __shfl_xor(acc[q].x, 16); acc[q].x += __shfl_xor(acc[q].x, 32);
      acc[q].y += __shfl_xor(acc[q].y, 16); acc[q].y += __shfl_xor(acc[q].y, 32);
    }
    // issue next node's first gather (eA2 arrived during combine)
    uint4 xlv2 = uint4{0u, 0u, 0u, 0u};
    if (n2 < N_NODES) xlv2 = xlxr4[(eA2 & 0xFFFFFu) * 32u + (uint)k];
    // epilogue (covers part of xlv2 latency)
    if (g == 0) {
      const float r = 1.f / fmaxf(den, 1e-16f);
      const v2f rr = v2f{r, r};
      const float4 b0 = ((const float4*)bias)[k * 2];
      const float4 b1 = ((const float4*)bias)[k * 2 + 1];
      const v2f bv[4] = {v2f{b0.x, b0.y}, v2f{b0.z, b0.w}, v2f{b1.x, b1.y}, v2f{b1.z, b1.w}};
      v2f ov[4];
#pragma unroll
      for (int q = 0; q < 4; q++) {
        ov[q] = __builtin_elementwise_max(acc[q] * rr + bv[q], zero);
        sv[q] += ov[q];
        qv[q] += ov[q] * ov[q];
      }
      float4* yp = (float4*)y + (size_t)n * 32 + (size_t)k * 2;
      yp[0] = make_float4(ov[0].x, ov[0].y, ov[1].x, ov[1].y);
      yp[1] = make_float4(ov[2].x, ov[2].y, ov[3].x, ov[3].y);
    }
    n = n2; ri = ri2; eA = eA2; xlv = xlv2;
  }
  if (l < 16) {
#pragma unroll
    for (int q = 0; q < 4; q++) {
      unsafeAtomicAdd(&bstat[k * 8 + 2 * q], sv[q].x);
      unsafeAtomicAdd(&bstat[k * 8 + 2 * q + 1], sv[q].y);
      unsafeAtomicAdd(&bstat[128 + k * 8 + 2 * q], qv[q].x);
      unsafeAtomicAdd(&bstat[128 + k * 8 + 2 * q + 1], qv[q].y);
    }
  }
  __syncthreads();
  partial[(size_t)tid * AGG_BLOCKS + blockIdx.x] = bstat[tid];
}

// ---------------- BN stats finalize: mean + rsqrt(var+eps) per channel ----------------
__global__ __launch_bounds__(256) void se_stats(const float* __restrict__ partial, float* __restrict__ musig) {
  __shared__ float red[256];
  const int ch = blockIdx.x, tid = threadIdx.x;
  float s = 0.f;
  for (int i = tid; i < AGG_BLOCKS; i += 256) s += partial[ch * AGG_BLOCKS + i];
  red[tid] = s; __syncthreads();
  for (int o = 128; o > 0; o >>= 1) { if (tid < o) red[tid] += red[tid + o]; __syncthreads(); }
  const float sum = red[0]; __syncthreads();
  float q = 0.f;
  for (int i = tid; i < AGG_BLOCKS; i += 256) q += partial[(128 + ch) * AGG_BLOCKS + i];
  red[tid] = q; __syncthreads();
  for (int o = 128; o > 0; o >>= 1) { if (tid < o) red[tid] += red[tid + o]; __syncthreads(); }
  if (tid == 0) {
    const float mean = sum / (float)N_NODES;
    const float var = red[0] / (float)N_NODES - mean * mean;
    musig[ch] = mean;
    musig[128 + ch] = rsqrtf(var + EPS_BN);
  }
}

// ---------------- BN apply (+ bf16 residual), y fp32 in; h bf16 in/out ----------------
__global__ void se_bn(const float* __restrict__ y, const float* __restrict__ musig,
                      const float* __restrict__ gamma, const float* __restrict__ beta,
                      ushort* __restrict__ h_bf, int residual) {
  int idx = blockIdx.x * 256 + threadIdx.x;     // one uint4 = 8 channels
  if (idx >= N_NODES * 16) return;
  const int k = idx & 15;                       // ch = k*8
  const float4 y0 = ((const float4*)y)[(size_t)idx * 2];
  const float4 y1 = ((const float4*)y)[(size_t)idx * 2 + 1];
  const float4 mu0 = ((const float4*)musig)[k * 2],         mu1 = ((const float4*)musig)[k * 2 + 1];
  const float4 rs0 = ((const float4*)(musig + 128))[k * 2], rs1 = ((const float4*)(musig + 128))[k * 2 + 1];
  const float4 g0  = ((const float4*)gamma)[k * 2],         g1  = ((const float4*)gamma)[k * 2 + 1];
  const float4 b0  = ((const float4*)beta)[k * 2],          b1  = ((const float4*)beta)[k * 2 + 1];
  float v[8];
  v[0] = g0.x * (y0.x - mu0.x) * rs0.x + b0.x;
  v[1] = g0.y * (y0.y - mu0.y) * rs0.y + b0.y;
  v[2] = g0.z * (y0.z - mu0.z) * rs0.z + b0.z;
  v[3] = g0.w * (y0.w - mu0.w) * rs0.w + b0.w;
  v[4] = g1.x * (y1.x - mu1.x) * rs1.x + b1.x;
  v[5] = g1.y * (y1.y - mu1.y) * rs1.y + b1.y;
  v[6] = g1.z * (y1.z - mu1.z) * rs1.z + b1.z;
  v[7] = g1.w * (y1.w - mu1.w) * rs1.w + b1.w;
  if (residual) {
    const uint4 ho = ((const uint4*)h_bf)[idx];
    float fr[8];
    unpack8(ho, fr);
#pragma unroll
    for (int j = 0; j < 8; j++) v[j] += fr[j];
  }
  uint4 p4;
  p4.x = ((uint)f2bf(v[1]) << 16) | f2bf(v[0]);
  p4.y = ((uint)f2bf(v[3]) << 16) | f2bf(v[2]);
  p4.z = ((uint)f2bf(v[5]) << 16) | f2bf(v[4]);
  p4.w = ((uint)f2bf(v[7]) << 16) | f2bf(v[6]);
  ((uint4*)h_bf)[idx] = p4;
}

// ---------------- mean pool: run-length register accumulation (batch sorted), global-atomic flush ----------------
__global__ __launch_bounds__(256) void se_pool(const ushort* __restrict__ h_bf,
                                               const int* __restrict__ batch,
                                               float* __restrict__ pool) {
  const int tid = threadIdx.x, w = tid >> 6, l = tid & 63;
  const int wid = blockIdx.x * 4 + w;
  const int nw = gridDim.x * 4;
  const int chunk = (N_NODES + nw - 1) / nw;
  const int start = wid * chunk;
  const int end = min(N_NODES, start + chunk);
  float a0 = 0.f, a1 = 0.f;
  int cg = -1, cnt = 0;
  for (int n = start; n < end; ++n) {
    const int gg = batch[n];
    if (gg != cg) {
      if (cg >= 0) {
        unsafeAtomicAdd(&pool[cg * HID + 2 * l], a0);
        unsafeAtomicAdd(&pool[cg * HID + 2 * l + 1], a1);
        if (l == 0) unsafeAtomicAdd(&pool[NGRAPH * HID + cg], (float)cnt);
      }
      a0 = 0.f; a1 = 0.f; cnt = 0; cg = gg;
    }
    const uint u = ((const uint*)h_bf)[(size_t)n * 64 + l];
    a0 += bf2f(u & 0xffffu);
    a1 += __uint_as_float(u & 0xffff0000u);
    cnt++;
  }
  if (cg >= 0) {
    unsafeAtomicAdd(&pool[cg * HID + 2 * l], a0);
    unsafeAtomicAdd(&pool[cg * HID + 2 * l + 1], a1);
    if (l == 0) unsafeAtomicAdd(&pool[NGRAPH * HID + cg], (float)cnt);
  }
}
__global__ void se_poolfin(const float* __restrict__ pool, float* __restrict__ out) {
  int idx = blockIdx.x * 256 + threadIdx.x;
  if (idx < NGRAPH * HID) {
    int g = idx >> 7;
    out[idx] = pool[idx] / fmaxf(pool[NGRAPH * HID + g], 1.f);
  }
}

extern "C" void kernel_launch(void* const* d_in, const int* in_sizes, int n_in,
                              void* d_out, int out_size, void* d_ws, size_t ws_size,
                              hipStream_t stream) {
  (void)in_sizes; (void)n_in; (void)out_size; (void)ws_size;
  const int*   tok_id  = (const int*)d_in[0];
  const float* bbox    = (const float*)d_in[1];
  const int*   ei      = (const int*)d_in[2];
  const int*   eattr   = (const int*)d_in[3];
  const int*   batch   = (const int*)d_in[4];
  const float* tok_emb = (const float*)d_in[5];
  const float* bbox_W  = (const float*)d_in[6];
  const float* bbox_b  = (const float*)d_in[7];
  const float* rel_emb = (const float*)d_in[8];
  const float* Wl0  = (const float*)d_in[9];
  const float* bl0  = (const float*)d_in[10];
  const float* Wr0  = (const float*)d_in[11];
  const float* br0  = (const float*)d_in[12];
  const float* We0  = (const float*)d_in[13];
  const float* att0 = (const float*)d_in[14];
  const float* bias0  = (const float*)d_in[15];
  const float* gamma0 = (const float*)d_in[16];
  const float* beta0  = (const float*)d_in[17];
  const float* WlS  = (const float*)d_in[18];
  const float* blS  = (const float*)d_in[19];
  const float* WrS  = (const float*)d_in[20];
  const float* brS  = (const float*)d_in[21];
  const float* WeS  = (const float*)d_in[22];
  const float* attS = (const float*)d_in[23];
  const float* biasS  = (const float*)d_in[24];
  const float* gammaS = (const float*)d_in[25];
  const float* betaS  = (const float*)d_in[26];
  float* out = (float*)d_out;

  char* ws = (char*)d_ws;
  size_t off = 0;
  auto alloc = [&](size_t bytes) -> char* {
    char* p = ws + off;
    off = (off + bytes + 255) & ~(size_t)255;
    return p;
  };
  ushort* xlxr = (ushort*)alloc((size_t)N_PAD * 256 * 2);
  float*  y    = (float*)alloc((size_t)N_NODES * HID * 4);
  ushort* h_bf = (ushort*)alloc((size_t)N_PAD * HID * 2);
  ushort* WST  = (ushort*)alloc((size_t)2 * 256 * HID * 2);
  float*  eetab   = (float*)alloc((size_t)3 * NREL * HID * 4);
  float*  biascat = (float*)alloc((size_t)3 * 256 * 4);
  float*  T    = (float*)alloc((size_t)NTOK * 256 * 4);
  float*  F    = (float*)alloc((size_t)4 * 256 * 4);
  float*  cvec = (float*)alloc((size_t)256 * 4);
  // deg | cur | pool contiguous -> single memset
  char*  z0   = ws + off;
  int*   deg  = (int*)alloc((size_t)N_NODES * 4);
  int*   cur  = (int*)alloc((size_t)N_NODES * 4);
  float* pool = (float*)alloc((size_t)(NGRAPH * HID + NGRAPH) * 4);
  size_t zlen = (size_t)((ws + off) - z0);
  int* offs = (int*)alloc((size_t)(N_NODES + 1) * 4);
  int* bsum = (int*)alloc(128 * 4);
  int2* rowinfo = (int2*)alloc((size_t)N_NODES * 8);
  uint* csrp = (uint*)alloc((size_t)(N_EDGES + 3 * N_NODES + 256) * 4);
  float* partial = (float*)alloc((size_t)256 * AGG_BLOCKS * 4);
  float* musig   = (float*)alloc(256 * 4);

  hipMemsetAsync(z0, 0, zlen, stream);

  se_prep<<<(PREP_TOT + 255) / 256, 256, 0, stream>>>(
      Wl0, Wr0, WlS, WrS, rel_emb, We0, WeS, bl0, br0, blS, brS,
      tok_emb, bbox_W, bbox_b, WST, eetab, biascat, T, F, cvec);
  se_hist<<<(N_EDGES + 255) / 256, 256, 0, stream>>>(ei, deg);
  se_scanA<<<98, 1024, 0, stream>>>(deg, offs, bsum);
  se_scanB<<<1, 128, 0, stream>>>(bsum, 98);
  se_scanC_pad<<<98, 1024, 0, stream>>>(offs, bsum, deg, csrp, rowinfo);
  se_scatter<<<(N_EDGES + 255) / 256, 256, 0, stream>>>(ei, eattr, offs, cur, csrp);

  // layer 0: folded transform (replaces build_x + K=288 GEMM)
  se_xform0<<<(N_NODES * 32 + 255) / 256, 256, 0, stream>>>(tok_id, bbox, T, F, cvec, xlxr);
  se_agg<<<AGG_BLOCKS, 256, 0, stream>>>((const uint4*)xlxr, csrp, rowinfo,
                                         eetab, att0, bias0, y, partial);
  se_stats<<<128, 256, 0, stream>>>(partial, musig);
  se_bn<<<(N_NODES * 16 + 255) / 256, 256, 0, stream>>>(y, musig, gamma0, beta0, h_bf, 0);

  // layers 1..2 (K=128)
  for (int li = 0; li < 2; ++li) {
    se_gemm<HID><<<dim3(N_PAD / 128, 2), 256, 0, stream>>>(h_bf, WST + (size_t)li * 256 * HID,
                                                           biascat + (li + 1) * 256, xlxr);
    se_agg<<<AGG_BLOCKS, 256, 0, stream>>>((const uint4*)xlxr, csrp, rowinfo,
                                           eetab + (size_t)(li + 1) * NREL * HID,
                                           attS + (size_t)li * NHEAD * NCH,
                                           biasS + (size_t)li * HID, y, partial);
    se_stats<<<128, 256, 0, stream>>>(partial, musig);
    se_bn<<<(N_NODES * 16 + 255) / 256, 256, 0, stream>>>(y, musig, gammaS + (size_t)li * HID,
                                                          betaS + (size_t)li * HID, h_bf, 1);
  }

  se_pool<<<POOL_BLOCKS, 256, 0, stream>>>(h_bf, batch, pool);
  se_poolfin<<<32, 256, 0, stream>>>(pool, out);
}